// Round 15
// baseline (698.656 us; speedup 1.0000x reference)
//
#include <hip/hip_runtime.h>
#include <hip/hip_bf16.h>

// TAGConv x2 GNN on MI355X. v15 = v14 with two fixes:
//  - gemmc: BM=128 x BK=32, 512 threads, 48KB LDS -> grid 391, >=2 resident
//    blocks/CU whose 28-tile latency chains fully overlap (was 782 blocks x
//    serial chains at 1 block-wave granularity).
//  - fill_edges: 4 dst-range passes -> esrc write region 0.4MB/pass stays in
//    L2, kills the 18x scatter write amplification (v12 profile: 55-62us).
//  - rest = v14: gemmn (A staged once), concat-K=896 layer 1, Horner layer 2,
//    wave-per-node 8-deep props.

#define EPS_MSG 1e-7f
#define BNSCALE 0.9999950000374997f  // 1/sqrt(1+1e-5)
#define LO_INV 0.0009765625f         // 2^-10

typedef _Float16 half_t;
typedef _Float16 f16x8 __attribute__((ext_vector_type(8)));
typedef float f32x4 __attribute__((ext_vector_type(4)));

__device__ __forceinline__ void gld16(const char* g, char* l) {
    __builtin_amdgcn_global_load_lds(
        (const __attribute__((address_space(1))) void*)g,
        (__attribute__((address_space(3))) void*)l, 16, 0, 0);
}

__device__ __forceinline__ float hlo(unsigned p) {
    unsigned short u = (unsigned short)(p & 0xffffu);
    half_t h;
    __builtin_memcpy(&h, &u, 2);
    return (float)h;
}
__device__ __forceinline__ float hhi(unsigned p) {
    unsigned short u = (unsigned short)(p >> 16);
    half_t h;
    __builtin_memcpy(&h, &u, 2);
    return (float)h;
}
__device__ __forceinline__ unsigned fpack2(float x, float y) {
    half_t a = (half_t)x, b = (half_t)y;
    unsigned short ua, ub;
    __builtin_memcpy(&ua, &a, 2);
    __builtin_memcpy(&ub, &b, 2);
    return (unsigned)ua | ((unsigned)ub << 16);
}

__device__ __forceinline__ float epi_apply(float v, int gc, int epi,
                                           const float* __restrict__ bias,
                                           const float* __restrict__ bng,
                                           const float* __restrict__ bnb) {
    if (epi == 1) {
        v += bias[gc];
    } else if (epi == 2) {
        v = bng[gc] * ((v + bias[gc]) * BNSCALE) + bnb[gc];
        v = fmaxf(v, 0.f);
    } else if (epi == 3) {
        v = fmaxf(v + bias[gc], 0.f);
    }
    return v;
}

// ---------------- CSR build ----------------

__global__ void zero_i32(int* __restrict__ p, int n) {
    int i = blockIdx.x * blockDim.x + threadIdx.x;
    if (i < n) p[i] = 0;
}

__global__ void count_deg(const int* __restrict__ col, int* __restrict__ deg, int E) {
    int e = blockIdx.x * blockDim.x + threadIdx.x;
    if (e < E) atomicAdd(&deg[col[e]], 1);
}

__global__ void compute_dis_s(const int* __restrict__ deg, float* __restrict__ dis,
                              float* __restrict__ s, float* __restrict__ rs, int N) {
    int v = blockIdx.x * blockDim.x + threadIdx.x;
    if (v >= N) return;
    int d = deg[v];
    float di = (d > 0) ? rsqrtf((float)d) : 0.f;
    dis[v] = di;
    s[v] = (d > 0) ? di : 1.f;
    rs[v] = (d > 0) ? sqrtf((float)d) : 1.f;
}

__global__ void scan_blk(const int* __restrict__ deg, int* __restrict__ off,
                         int* __restrict__ bsum, int N) {
    __shared__ int sm[1024];
    int i = blockIdx.x * 1024 + threadIdx.x;
    sm[threadIdx.x] = (i < N) ? deg[i] : 0;
    __syncthreads();
    for (int ofs = 1; ofs < 1024; ofs <<= 1) {
        int t = (threadIdx.x >= (unsigned)ofs) ? sm[threadIdx.x - ofs] : 0;
        __syncthreads();
        sm[threadIdx.x] += t;
        __syncthreads();
    }
    if (i < N) off[i + 1] = sm[threadIdx.x];
    if (threadIdx.x == 0) bsum[blockIdx.x] = sm[1023];
}

__global__ void scan_top(int* __restrict__ bsum, int nb) {
    if (threadIdx.x == 0 && blockIdx.x == 0) {
        int a = 0;
        for (int b = 0; b < nb; ++b) {
            int t = bsum[b];
            bsum[b] = a;
            a += t;
        }
    }
}

__global__ void scan_add(int* __restrict__ off, const int* __restrict__ bsum, int N) {
    int i = blockIdx.x * 1024 + threadIdx.x;
    if (i < N) off[i + 1] += bsum[blockIdx.x];
    if (i == 0) off[0] = 0;
}

// dst-range pass: only edges with col in [lo,hi) -> esrc writes stay L2-local
__global__ void fill_edges(const int* __restrict__ row, const int* __restrict__ col,
                           const int* __restrict__ off, int* __restrict__ cur,
                           unsigned short* __restrict__ esrc, int E, int lo, int hi) {
    int e = blockIdx.x * blockDim.x + threadIdx.x;
    if (e >= E) return;
    int c = col[e];
    if (c < lo || c >= hi) return;
    int pos = off[c] + atomicAdd(&cur[c], 1);
    esrc[pos] = (unsigned short)row[e];
}

// ---------------- conversions ----------------

__global__ void conv_xg(const float* __restrict__ x, half_t* __restrict__ slab,
                        half_t* __restrict__ g0, const float* __restrict__ dis,
                        const float* __restrict__ s, int total) {
    int i = blockIdx.x * blockDim.x + threadIdx.x;
    if (i >= total) return;
    int v = i >> 7, c = i & 127;
    float xv = x[i];
    slab[(size_t)v * 896 + c] = (half_t)(s[v] * xv);
    g0[i] = (half_t)(dis[v] * fmaxf(xv, 0.f));
}

__device__ __forceinline__ void wcv(const float* __restrict__ in, half_t* __restrict__ oh,
                                    half_t* __restrict__ ol, int nm, int K, int Nn, int i) {
    int KT = nm * K;
    int n = i / KT;
    int rem = i - n * KT;
    int km = rem / K, k = rem - km * K;
    float w = in[(size_t)km * K * Nn + (size_t)k * Nn + n];
    half_t h = (half_t)w;
    oh[i] = h;
    ol[i] = (half_t)((w - (float)h) * 1024.f);
}

__global__ void conv_all(const float* l1, const float* l2, const float* a1, const float* b1,
                         const float* a2, const float* b2, half_t* W1h, half_t* W1l,
                         half_t* W2h, half_t* W2l, half_t* M1ah, half_t* M1al, half_t* M1bh,
                         half_t* M1bl, half_t* M2ah, half_t* M2al, half_t* M2bh,
                         half_t* M2bl) {
    int i = blockIdx.x * blockDim.x + threadIdx.x;
    if (i < 114688) {
        wcv(l1, W1h, W1l, 7, 128, 128, i);  // concat-K layout for layer-1
    } else if (i < 172032) {
        // W2: concat-N layout. B^T[np][k], np = km*64+n, value = l2[km][k][n]
        int j = i - 114688;
        int np = j >> 7, k = j & 127;
        int km = np >> 6, n = np & 63;
        float w = l2[(size_t)km * 128 * 64 + (size_t)k * 64 + n];
        half_t h = (half_t)w;
        W2h[j] = h;
        W2l[j] = (half_t)((w - (float)h) * 1024.f);
    } else if (i < 204800) {
        wcv(a1, M1ah, M1al, 1, 128, 256, i - 172032);
    } else if (i < 237568) {
        wcv(b1, M1bh, M1bl, 1, 256, 128, i - 204800);
    } else if (i < 245760) {
        wcv(a2, M2ah, M2al, 1, 64, 128, i - 237568);
    } else if (i < 253952) {
        wcv(b2, M2bh, M2bl, 1, 128, 64, i - 245760);
    }
}

// T[j][c] = sum_{k=j+1..6} sum_kk l2[k][kk][c], j=0..5  (parallel, 6 blocks)
__global__ void conv_trows(const float* __restrict__ l2, float* __restrict__ T) {
    __shared__ float sm[256];
    int j = blockIdx.x;
    int c = threadIdx.x & 63;
    int part = threadIdx.x >> 6;
    float a = 0.f;
    for (int k = j + 1; k <= 6; ++k)
        for (int kk = part; kk < 128; kk += 4)
            a += l2[(size_t)k * 128 * 64 + kk * 64 + c];
    sm[threadIdx.x] = a;
    __syncthreads();
    if (part == 0) T[j * 64 + c] = (sm[c] + sm[64 + c]) + (sm[128 + c] + sm[192 + c]);
}

// ---------------- propagation, 128ch (layer 1), 8-deep ----------------

__global__ void __launch_bounds__(256) prop(const unsigned* __restrict__ gin, int idl,
                                            unsigned* __restrict__ gout, int odl,
                                            const float* __restrict__ dis,
                                            const int* __restrict__ off,
                                            const unsigned short* __restrict__ esrc, int N) {
    const int lane = threadIdx.x & 63;
    const int w = threadIdx.x >> 6;
    const int stride = gridDim.x * 4;
    for (int v = blockIdx.x * 4 + w; v < N; v += stride) {
        int s = off[v], e = off[v + 1];
        float2 A0 = {0.f, 0.f}, A1 = {0.f, 0.f}, A2 = {0.f, 0.f}, A3 = {0.f, 0.f};
        float2 A4 = {0.f, 0.f}, A5 = {0.f, 0.f}, A6 = {0.f, 0.f}, A7 = {0.f, 0.f};
        for (int i = s; i < e; i += 8) {
            unsigned p[8];
            int ok[8];
#pragma unroll
            for (int j = 0; j < 8; ++j) {
                int ij = i + j;
                ok[j] = ij < e;
                int idx = ok[j] ? ij : e - 1;
                p[j] = gin[esrc[idx] * idl + lane];
            }
            A0.x += ok[0] ? hlo(p[0]) : 0.f; A0.y += ok[0] ? hhi(p[0]) : 0.f;
            A1.x += ok[1] ? hlo(p[1]) : 0.f; A1.y += ok[1] ? hhi(p[1]) : 0.f;
            A2.x += ok[2] ? hlo(p[2]) : 0.f; A2.y += ok[2] ? hhi(p[2]) : 0.f;
            A3.x += ok[3] ? hlo(p[3]) : 0.f; A3.y += ok[3] ? hhi(p[3]) : 0.f;
            A4.x += ok[4] ? hlo(p[4]) : 0.f; A4.y += ok[4] ? hhi(p[4]) : 0.f;
            A5.x += ok[5] ? hlo(p[5]) : 0.f; A5.y += ok[5] ? hhi(p[5]) : 0.f;
            A6.x += ok[6] ? hlo(p[6]) : 0.f; A6.y += ok[6] ? hhi(p[6]) : 0.f;
            A7.x += ok[7] ? hlo(p[7]) : 0.f; A7.y += ok[7] ? hhi(p[7]) : 0.f;
        }
        float ax = ((A0.x + A1.x) + (A2.x + A3.x)) + ((A4.x + A5.x) + (A6.x + A7.x));
        float ay = ((A0.y + A1.y) + (A2.y + A3.y)) + ((A4.y + A5.y) + (A6.y + A7.y));
        float dv = dis[v];
        float ce = (float)(e - s) * EPS_MSG;
        float hx = fmaf(dv, ax, ce);
        float hy = fmaf(dv, ay, ce);
        gout[v * odl + lane] = fpack2(dv * hx, dv * hy);
    }
}

// ---------------- propagation, 64ch Horner step (layer 2), 8-deep ----------

template <int FINAL>
__global__ void __launch_bounds__(256) prop64(
    const half_t* __restrict__ uin, int ldu, const half_t* __restrict__ pj, int ldp,
    half_t* __restrict__ uout, int ldo, const float* __restrict__ dis,
    const int* __restrict__ off, const unsigned short* __restrict__ esrc,
    const float* __restrict__ tj, const float* __restrict__ bias2, int N) {
    const int c = threadIdx.x & 63;
    const int w = threadIdx.x >> 6;
    const int stride = gridDim.x * 4;
    for (int v = blockIdx.x * 4 + w; v < N; v += stride) {
        int s = off[v], e = off[v + 1];
        float a0 = 0.f, a1 = 0.f, a2 = 0.f, a3 = 0.f;
        float a4 = 0.f, a5 = 0.f, a6 = 0.f, a7 = 0.f;
        for (int i = s; i < e; i += 8) {
            float q[8];
            int ok[8];
#pragma unroll
            for (int j = 0; j < 8; ++j) {
                int ij = i + j;
                ok[j] = ij < e;
                int idx = ok[j] ? ij : e - 1;
                q[j] = (float)uin[(size_t)esrc[idx] * ldu + c];
            }
            a0 += ok[0] ? q[0] : 0.f;
            a1 += ok[1] ? q[1] : 0.f;
            a2 += ok[2] ? q[2] : 0.f;
            a3 += ok[3] ? q[3] : 0.f;
            a4 += ok[4] ? q[4] : 0.f;
            a5 += ok[5] ? q[5] : 0.f;
            a6 += ok[6] ? q[6] : 0.f;
            a7 += ok[7] ? q[7] : 0.f;
        }
        float acc = ((a0 + a1) + (a2 + a3)) + ((a4 + a5) + (a6 + a7));
        float dv = dis[v];
        float base = (float)pj[(size_t)v * ldp + c] + (float)(e - s) * EPS_MSG * tj[c];
        float u = fmaf(dv, acc, base);
        if (FINAL)
            uout[(size_t)v * ldo + c] = (half_t)(u + bias2[c]);
        else
            uout[(size_t)v * ldo + c] = (half_t)(dv * u);
    }
}

// ---------------- concat GEMM: BM=128, BN=128, BK=32, 512 thr, dbuf ---------
// C[M,128] = bias + rs .* (A[M,K] @ (Bh + Bl/1024)^T)

__global__ __launch_bounds__(512) void gemmc(
    int M, int kiters, const half_t* __restrict__ A, int lda,
    const half_t* __restrict__ Bhp, const half_t* __restrict__ Blp, int ldb,
    half_t* __restrict__ Cp, int ldc, const float* __restrict__ rs,
    const float* __restrict__ bias) {
    constexpr int ABY = 8192, BBY = 8192, BUFBY = ABY + 2 * BBY;  // 24576
    __shared__ __align__(16) char lds[2][BUFBY];

    const int tid = threadIdx.x, lane = tid & 63, w = tid >> 6;  // 8 waves
    const int wr = w >> 1, wc = w & 1;
    const int m0 = blockIdx.x * 128;
    const int l15 = lane & 15, lq = lane >> 4;
    const int lr = lane >> 2, lc = lane & 3;

    const char* gA = (const char*)A;
    const char* gBh = (const char*)Bhp;
    const char* gBl = (const char*)Blp;
    const size_t ldaB = (size_t)lda * 2, ldbB = (size_t)ldb * 2;

    auto stage = [&](int kt, int buf) {
        const int k0b = kt * 64;
        char* base = lds[0] + buf * BUFBY;
        int r = w * 16 + lr;
        int sc = (lc ^ (r & 3)) << 4;
        {  // A: 8 chunks (rows w*16..w*16+15)
            int gv = m0 + r;
            if (gv >= M) gv = M - 1;
            gld16(gA + (size_t)gv * ldaB + k0b + sc, base + w * 1024);
        }
        {  // B: 8 chunks per plane
            size_t goff = (size_t)r * ldbB + k0b + sc;
            gld16(gBh + goff, base + ABY + w * 1024);
            gld16(gBl + goff, base + ABY + BBY + w * 1024);
        }
    };

    f32x4 acch[2][4], accl[2][4];
#pragma unroll
    for (int fm = 0; fm < 2; ++fm)
#pragma unroll
        for (int fn = 0; fn < 4; ++fn) {
            acch[fm][fn] = (f32x4){0.f, 0.f, 0.f, 0.f};
            accl[fm][fn] = (f32x4){0.f, 0.f, 0.f, 0.f};
        }

    auto compute = [&](int buf) {
        const char* Ab = lds[0] + buf * BUFBY;
        const char* Bhb = Ab + ABY;
        const char* Blb = Ab + ABY + BBY;
        f16x8 af[2];
#pragma unroll
        for (int fm = 0; fm < 2; ++fm) {
            int ra = wr * 32 + fm * 16 + l15;
            af[fm] = *(const f16x8*)(Ab + ra * 64 + ((lq ^ (ra & 3)) << 4));
        }
#pragma unroll
        for (int fn = 0; fn < 4; ++fn) {
            int rb = wc * 64 + fn * 16 + l15;
            int o = rb * 64 + ((lq ^ (rb & 3)) << 4);
            f16x8 bhv = *(const f16x8*)(Bhb + o);
            f16x8 blv = *(const f16x8*)(Blb + o);
#pragma unroll
            for (int fm = 0; fm < 2; ++fm) {
                acch[fm][fn] = __builtin_amdgcn_mfma_f32_16x16x32_f16(af[fm], bhv, acch[fm][fn], 0, 0, 0);
                accl[fm][fn] = __builtin_amdgcn_mfma_f32_16x16x32_f16(af[fm], blv, accl[fm][fn], 0, 0, 0);
            }
        }
    };

    stage(0, 0);
    int buf = 0;
    for (int kt = 0; kt < kiters; ++kt) {
        __syncthreads();
        if (kt + 1 < kiters) stage(kt + 1, buf ^ 1);
        compute(buf);
        buf ^= 1;
    }

#pragma unroll
    for (int fm = 0; fm < 2; ++fm)
#pragma unroll
        for (int fn = 0; fn < 4; ++fn)
#pragma unroll
            for (int i = 0; i < 4; ++i) {
                int gr = m0 + wr * 32 + fm * 16 + lq * 4 + i;
                if (gr >= M) continue;
                int gc = wc * 64 + fn * 16 + l15;
                float v = acch[fm][fn][i] + accl[fm][fn][i] * LO_INV;
                v = v * rs[gr] + bias[gc];
                Cp[(size_t)gr * ldc + gc] = (half_t)v;
            }
}

// ---------------- loop-N GEMM: A staged once, B dbuf per strip-tile ----------
// C[M, NS*64](ldc) = epi( A[M,KT] @ (Bh + Bl/1024)^T ); strip scaleStrip rows
// pre-scaled by scaleRows.

template <int KT, int NS, int OUTF32>
__global__ __launch_bounds__(256) void gemmn(
    int M, const half_t* __restrict__ A, int lda, const half_t* __restrict__ Bhp,
    const half_t* __restrict__ Blp, int ldb, void* __restrict__ Cp, int ldc, int epi,
    const float* __restrict__ bias, const float* __restrict__ bng,
    const float* __restrict__ bnb, const float* __restrict__ scaleRows, int scaleStrip) {
    constexpr int KI = KT / 32;
    constexpr int T = NS * KI;
    constexpr int CPR = KT / 8;  // 16B cols per A row
    constexpr int LPR = CPR;     // lanes per row
    constexpr int RPC = 64 / LPR;
    constexpr int SW = (CPR < 16) ? CPR - 1 : 15;
    constexpr int ACH = (64 * KT * 2) / 1024;
    constexpr int ACW = ACH / 4;
    constexpr int ABY = 64 * KT * 2;
    constexpr int BPB = 4096;
    __shared__ __align__(16) char lds[ABY + 4 * BPB];

    const int tid = threadIdx.x, lane = tid & 63, w = tid >> 6;
    const int m0 = blockIdx.x * 64;
    const int l15 = lane & 15, lq = lane >> 4;
    const int lr = lane >> 2, lc = lane & 3;

    const char* gA = (const char*)A;
    const char* gBh = (const char*)Bhp;
    const char* gBl = (const char*)Blp;
    const size_t ldaB = (size_t)lda * 2, ldbB = (size_t)ldb * 2;

    // stage A once
#pragma unroll
    for (int i = 0; i < ACW; ++i) {
        int c = w * ACW + i;
        int r = c * RPC + lane / LPR;
        int col = lane % LPR;
        int scol = col ^ (r & SW);
        int gv = m0 + r;
        if (gv >= M) gv = M - 1;
        gld16(gA + (size_t)gv * ldaB + scol * 16, lds + c * 1024);
    }

    auto stageB = [&](int ns, int kt, int buf) {
        char* bb = lds + ABY + buf * 2 * BPB;
        int r = w * 16 + lr;  // 4 chunks, one per wave
        int sc = (lc ^ (r & 3)) << 4;
        size_t goff = (size_t)(ns * 64 + r) * ldbB + kt * 64 + sc;
        gld16(gBh + goff, bb + w * 1024);
        gld16(gBl + goff, bb + BPB + w * 1024);
    };

    f32x4 acch[4], accl[4];

    auto compute = [&](int buf, int kt) {
        const char* Ab = lds;
        const char* Bhb = lds + ABY + buf * 2 * BPB;
        const char* Blb = Bhb + BPB;
        int ra = w * 16 + l15;
        int cc = kt * 4 + lq;
        f16x8 af = *(const f16x8*)(Ab + ra * (KT * 2) + ((cc ^ (ra & SW)) << 4));
#pragma unroll
        for (int fn = 0; fn < 4; ++fn) {
            int rb = fn * 16 + l15;
            int o = rb * 64 + ((lq ^ (rb & 3)) << 4);
            f16x8 bhv = *(const f16x8*)(Bhb + o);
            f16x8 blv = *(const f16x8*)(Blb + o);
            acch[fn] = __builtin_amdgcn_mfma_f32_16x16x32_f16(af, bhv, acch[fn], 0, 0, 0);
            accl[fn] = __builtin_amdgcn_mfma_f32_16x16x32_f16(af, blv, accl[fn], 0, 0, 0);
        }
    };

    stageB(0, 0, 0);
    int buf = 0;
    for (int t = 0; t < T; ++t) {
        int ns = t / KI, kt = t - ns * KI;
        __syncthreads();
        if (t + 1 < T) {
            int t1 = t + 1;
            stageB(t1 / KI, t1 - (t1 / KI) * KI, buf ^ 1);
        }
        if (kt == 0) {
#pragma unroll
            for (int fn = 0; fn < 4; ++fn) {
                acch[fn] = (f32x4){0.f, 0.f, 0.f, 0.f};
                accl[fn] = (f32x4){0.f, 0.f, 0.f, 0.f};
            }
        }
        compute(buf, kt);
        if (kt == KI - 1) {
#pragma unroll
            for (int fn = 0; fn < 4; ++fn)
#pragma unroll
                for (int i = 0; i < 4; ++i) {
                    int gr = m0 + w * 16 + lq * 4 + i;
                    if (gr >= M) continue;
                    int gc = ns * 64 + fn * 16 + l15;
                    float v = acch[fn][i] + accl[fn][i] * LO_INV;
                    if (ns == scaleStrip) v *= scaleRows[gr];
                    v = epi_apply(v, gc, epi, bias, bng, bnb);
                    if (OUTF32)
                        ((float*)Cp)[(size_t)gr * ldc + gc] = v;
                    else
                        ((half_t*)Cp)[(size_t)gr * ldc + gc] = (half_t)v;
                }
        }
        buf ^= 1;
    }
}

extern "C" void kernel_launch(void* const* d_in, const int* in_sizes, int n_in,
                              void* d_out, int out_size, void* d_ws, size_t ws_size,
                              hipStream_t stream) {
    const float* x     = (const float*)d_in[0];
    const int*   ei    = (const int*)d_in[1];
    const float* lins1 = (const float*)d_in[2];
    const float* bias1 = (const float*)d_in[3];
    const float* m1w1  = (const float*)d_in[4];
    const float* m1b1  = (const float*)d_in[5];
    const float* bn1g  = (const float*)d_in[6];
    const float* bn1b  = (const float*)d_in[7];
    const float* m1w2  = (const float*)d_in[8];
    const float* m1b2  = (const float*)d_in[9];
    const float* lins2 = (const float*)d_in[10];
    const float* bias2 = (const float*)d_in[11];
    const float* m2w1  = (const float*)d_in[12];
    const float* m2b1  = (const float*)d_in[13];
    const float* bn2g  = (const float*)d_in[14];
    const float* bn2b  = (const float*)d_in[15];
    const float* m2w2  = (const float*)d_in[16];
    const float* m2b2  = (const float*)d_in[17];
    float* out = (float*)d_out;

    const int N = in_sizes[0] / 128;
    const int E = in_sizes[1] / 2;
    const int* row = ei;
    const int* col = ei + E;

    char* ws = (char*)d_ws;
    size_t o = 0;
    auto alloc = [&](size_t bytes) {
        void* p = ws + o;
        o += (bytes + 255) & ~(size_t)255;
        return p;
    };
    int*            deg  = (int*)alloc((size_t)N * 4);
    int*            cur  = (int*)alloc((size_t)N * 4);
    float*          dis  = (float*)alloc((size_t)N * 4);
    float*          sA   = (float*)alloc((size_t)N * 4);
    float*          rsA  = (float*)alloc((size_t)N * 4);
    int*            off  = (int*)alloc((size_t)(N + 1) * 4);
    int*            bsum = (int*)alloc(1024 * 4);
    float*          Trow = (float*)alloc(6 * 64 * 4);
    unsigned short* esrc = (unsigned short*)alloc((size_t)E * 2);
    half_t* g0    = (half_t*)alloc((size_t)N * 128 * 2);
    half_t* ACC   = (half_t*)alloc((size_t)N * 128 * 2);
    half_t* Z     = (half_t*)alloc((size_t)N * 256 * 2);
    half_t* H1    = (half_t*)alloc((size_t)N * 128 * 2);
    half_t* ACC2  = (half_t*)alloc((size_t)N * 64 * 2);
    half_t* Wc1h  = (half_t*)alloc((size_t)128 * 896 * 2);
    half_t* Wc1l  = (half_t*)alloc((size_t)128 * 896 * 2);
    half_t* Wc2h  = (half_t*)alloc((size_t)448 * 128 * 2);
    half_t* Wc2l  = (half_t*)alloc((size_t)448 * 128 * 2);
    half_t* Wm1ah = (half_t*)alloc((size_t)256 * 128 * 2);
    half_t* Wm1al = (half_t*)alloc((size_t)256 * 128 * 2);
    half_t* Wm1bh = (half_t*)alloc((size_t)128 * 256 * 2);
    half_t* Wm1bl = (half_t*)alloc((size_t)128 * 256 * 2);
    half_t* Wm2ah = (half_t*)alloc((size_t)128 * 64 * 2);
    half_t* Wm2al = (half_t*)alloc((size_t)128 * 64 * 2);
    half_t* Wm2bh = (half_t*)alloc((size_t)64 * 128 * 2);
    half_t* Wm2bl = (half_t*)alloc((size_t)64 * 128 * 2);
    half_t* slab  = (half_t*)alloc((size_t)N * 896 * 2);
    (void)ws_size;

    const int TPB = 256;
    const int nb = (N + 1023) / 1024;
    zero_i32<<<(N + TPB - 1) / TPB, TPB, 0, stream>>>(deg, N);
    zero_i32<<<(N + TPB - 1) / TPB, TPB, 0, stream>>>(cur, N);
    count_deg<<<(E + TPB - 1) / TPB, TPB, 0, stream>>>(col, deg, E);
    compute_dis_s<<<(N + TPB - 1) / TPB, TPB, 0, stream>>>(deg, dis, sA, rsA, N);
    scan_blk<<<nb, 1024, 0, stream>>>(deg, off, bsum, N);
    scan_top<<<1, 64, 0, stream>>>(bsum, nb);
    scan_add<<<nb, 1024, 0, stream>>>(off, bsum, N);
    {
        int qn = (N + 3) / 4;
        for (int p = 0; p < 4; ++p) {
            int lo = p * qn, hi = (p == 3) ? N : (p + 1) * qn;
            fill_edges<<<(E + TPB - 1) / TPB, TPB, 0, stream>>>(row, col, off, cur, esrc, E,
                                                                lo, hi);
        }
    }
    conv_all<<<(253952 + TPB - 1) / TPB, TPB, 0, stream>>>(
        lins1, lins2, m1w1, m1w2, m2w1, m2w2, Wc1h, Wc1l, Wc2h, Wc2l, Wm1ah, Wm1al, Wm1bh,
        Wm1bl, Wm2ah, Wm2al, Wm2bh, Wm2bl);
    conv_trows<<<6, 256, 0, stream>>>(lins2, Trow);
    conv_xg<<<(N * 128 + TPB - 1) / TPB, TPB, 0, stream>>>(x, slab, g0, dis, sA, N * 128);

    unsigned* slabU = (unsigned*)slab;
    unsigned* g0U = (unsigned*)g0;
    const int HG = (N + 63) / 64;
    const int HG128 = (N + 127) / 128;

    // ---- Layer 1: 6 props @128ch into slab cols 1..6, concat-K GEMM ----
    prop<<<2048, 256, 0, stream>>>(g0U, 64, slabU + 64, 448, dis, off, esrc, N);
    for (int k = 2; k <= 6; ++k)
        prop<<<2048, 256, 0, stream>>>(slabU + (size_t)(k - 1) * 64, 448,
                                       slabU + (size_t)k * 64, 448, dis, off, esrc, N);
    gemmc<<<HG128, 512, 0, stream>>>(N, 28, slab, 896, Wc1h, Wc1l, 896, ACC, 128, rsA, bias1);
    // MLP1: Z = relu(bn(ACC@W+b)); h1 = relu(Z@W+b) -> H1
    gemmn<128, 4, 0><<<HG, 256, 0, stream>>>(
        N, ACC, 128, Wm1ah, Wm1al, 128, Z, 256, 2, m1b1, bn1g, bn1b, nullptr, -1);
    gemmn<256, 2, 0><<<HG, 256, 0, stream>>>(
        N, Z, 256, Wm1bh, Wm1bl, 256, H1, 128, 3, m1b2, nullptr, nullptr, nullptr, -1);

    // ---- Layer 2: P = H1 @ [W2_0..W2_6] (concat-N); strip 6 pre-scaled by dis ----
    gemmn<128, 7, 0><<<HG, 256, 0, stream>>>(
        N, H1, 128, Wc2h, Wc2l, 128, slab, 448, 0, nullptr, nullptr, nullptr, dis, 6);

    // ---- Horner: u <- p_j + EPS*indeg*t_j + M u, 6 steps @64ch ----
    half_t* ub0 = g0;
    half_t* ub1 = g0 + (size_t)N * 64;
    prop64<0><<<2048, 256, 0, stream>>>(slab + 384, 448, slab + 320, 448, ub0, 64, dis, off,
                                        esrc, Trow + 5 * 64, nullptr, N);
    prop64<0><<<2048, 256, 0, stream>>>(ub0, 64, slab + 256, 448, ub1, 64, dis, off, esrc,
                                        Trow + 4 * 64, nullptr, N);
    prop64<0><<<2048, 256, 0, stream>>>(ub1, 64, slab + 192, 448, ub0, 64, dis, off, esrc,
                                        Trow + 3 * 64, nullptr, N);
    prop64<0><<<2048, 256, 0, stream>>>(ub0, 64, slab + 128, 448, ub1, 64, dis, off, esrc,
                                        Trow + 2 * 64, nullptr, N);
    prop64<0><<<2048, 256, 0, stream>>>(ub1, 64, slab + 64, 448, ub0, 64, dis, off, esrc,
                                        Trow + 1 * 64, nullptr, N);
    prop64<1><<<2048, 256, 0, stream>>>(ub0, 64, slab, 448, ACC2, 64, dis, off, esrc,
                                        Trow + 0 * 64, bias2, N);

    // ---- MLP2 ----
    gemmn<64, 2, 0><<<HG, 256, 0, stream>>>(
        N, ACC2, 64, Wm2ah, Wm2al, 64, Z, 128, 2, m2b1, bn2g, bn2b, nullptr, -1);
    gemmn<128, 1, 1><<<HG, 256, 0, stream>>>(
        N, Z, 128, Wm2bh, Wm2bl, 128, out, 64, 1, m2b2, nullptr, nullptr, nullptr, -1);
}

// Round 16
// 673.287 us; speedup vs baseline: 1.0377x; 1.0377x over previous
//
#include <hip/hip_runtime.h>
#include <hip/hip_bf16.h>

// TAGConv x2 GNN on MI355X. v16 = v15 with:
//  - fill_edges reverted to SINGLE pass (4-pass scan tax > scatter savings)
//  - conv_trows -> 2-stage parallel reduce (48 blocks + 1 block; was 6-block
//    serial loop costing 46.8us at 0.14% occupancy)
//  - gemmc stays BM=128 x BK=32 x 512thr (measured better than v14's BM=64)
//  - rest = v14/v15: gemmn (A staged once), concat-K=896 layer 1, Horner
//    layer 2, wave-per-node 8-deep props.

#define EPS_MSG 1e-7f
#define BNSCALE 0.9999950000374997f  // 1/sqrt(1+1e-5)
#define LO_INV 0.0009765625f         // 2^-10

typedef _Float16 half_t;
typedef _Float16 f16x8 __attribute__((ext_vector_type(8)));
typedef float f32x4 __attribute__((ext_vector_type(4)));

__device__ __forceinline__ void gld16(const char* g, char* l) {
    __builtin_amdgcn_global_load_lds(
        (const __attribute__((address_space(1))) void*)g,
        (__attribute__((address_space(3))) void*)l, 16, 0, 0);
}

__device__ __forceinline__ float hlo(unsigned p) {
    unsigned short u = (unsigned short)(p & 0xffffu);
    half_t h;
    __builtin_memcpy(&h, &u, 2);
    return (float)h;
}
__device__ __forceinline__ float hhi(unsigned p) {
    unsigned short u = (unsigned short)(p >> 16);
    half_t h;
    __builtin_memcpy(&h, &u, 2);
    return (float)h;
}
__device__ __forceinline__ unsigned fpack2(float x, float y) {
    half_t a = (half_t)x, b = (half_t)y;
    unsigned short ua, ub;
    __builtin_memcpy(&ua, &a, 2);
    __builtin_memcpy(&ub, &b, 2);
    return (unsigned)ua | ((unsigned)ub << 16);
}

__device__ __forceinline__ float epi_apply(float v, int gc, int epi,
                                           const float* __restrict__ bias,
                                           const float* __restrict__ bng,
                                           const float* __restrict__ bnb) {
    if (epi == 1) {
        v += bias[gc];
    } else if (epi == 2) {
        v = bng[gc] * ((v + bias[gc]) * BNSCALE) + bnb[gc];
        v = fmaxf(v, 0.f);
    } else if (epi == 3) {
        v = fmaxf(v + bias[gc], 0.f);
    }
    return v;
}

// ---------------- CSR build ----------------

__global__ void zero_i32(int* __restrict__ p, int n) {
    int i = blockIdx.x * blockDim.x + threadIdx.x;
    if (i < n) p[i] = 0;
}

__global__ void count_deg(const int* __restrict__ col, int* __restrict__ deg, int E) {
    int e = blockIdx.x * blockDim.x + threadIdx.x;
    if (e < E) atomicAdd(&deg[col[e]], 1);
}

__global__ void compute_dis_s(const int* __restrict__ deg, float* __restrict__ dis,
                              float* __restrict__ s, float* __restrict__ rs, int N) {
    int v = blockIdx.x * blockDim.x + threadIdx.x;
    if (v >= N) return;
    int d = deg[v];
    float di = (d > 0) ? rsqrtf((float)d) : 0.f;
    dis[v] = di;
    s[v] = (d > 0) ? di : 1.f;
    rs[v] = (d > 0) ? sqrtf((float)d) : 1.f;
}

__global__ void scan_blk(const int* __restrict__ deg, int* __restrict__ off,
                         int* __restrict__ bsum, int N) {
    __shared__ int sm[1024];
    int i = blockIdx.x * 1024 + threadIdx.x;
    sm[threadIdx.x] = (i < N) ? deg[i] : 0;
    __syncthreads();
    for (int ofs = 1; ofs < 1024; ofs <<= 1) {
        int t = (threadIdx.x >= (unsigned)ofs) ? sm[threadIdx.x - ofs] : 0;
        __syncthreads();
        sm[threadIdx.x] += t;
        __syncthreads();
    }
    if (i < N) off[i + 1] = sm[threadIdx.x];
    if (threadIdx.x == 0) bsum[blockIdx.x] = sm[1023];
}

__global__ void scan_top(int* __restrict__ bsum, int nb) {
    if (threadIdx.x == 0 && blockIdx.x == 0) {
        int a = 0;
        for (int b = 0; b < nb; ++b) {
            int t = bsum[b];
            bsum[b] = a;
            a += t;
        }
    }
}

__global__ void scan_add(int* __restrict__ off, const int* __restrict__ bsum, int N) {
    int i = blockIdx.x * 1024 + threadIdx.x;
    if (i < N) off[i + 1] += bsum[blockIdx.x];
    if (i == 0) off[0] = 0;
}

__global__ void fill_edges(const int* __restrict__ row, const int* __restrict__ col,
                           const int* __restrict__ off, int* __restrict__ cur,
                           unsigned short* __restrict__ esrc, int E) {
    int e = blockIdx.x * blockDim.x + threadIdx.x;
    if (e >= E) return;
    int c = col[e];
    int pos = off[c] + atomicAdd(&cur[c], 1);
    esrc[pos] = (unsigned short)row[e];
}

// ---------------- conversions ----------------

__global__ void conv_xg(const float* __restrict__ x, half_t* __restrict__ slab,
                        half_t* __restrict__ g0, const float* __restrict__ dis,
                        const float* __restrict__ s, int total) {
    int i = blockIdx.x * blockDim.x + threadIdx.x;
    if (i >= total) return;
    int v = i >> 7, c = i & 127;
    float xv = x[i];
    slab[(size_t)v * 896 + c] = (half_t)(s[v] * xv);
    g0[i] = (half_t)(dis[v] * fmaxf(xv, 0.f));
}

__device__ __forceinline__ void wcv(const float* __restrict__ in, half_t* __restrict__ oh,
                                    half_t* __restrict__ ol, int nm, int K, int Nn, int i) {
    int KT = nm * K;
    int n = i / KT;
    int rem = i - n * KT;
    int km = rem / K, k = rem - km * K;
    float w = in[(size_t)km * K * Nn + (size_t)k * Nn + n];
    half_t h = (half_t)w;
    oh[i] = h;
    ol[i] = (half_t)((w - (float)h) * 1024.f);
}

__global__ void conv_all(const float* l1, const float* l2, const float* a1, const float* b1,
                         const float* a2, const float* b2, half_t* W1h, half_t* W1l,
                         half_t* W2h, half_t* W2l, half_t* M1ah, half_t* M1al, half_t* M1bh,
                         half_t* M1bl, half_t* M2ah, half_t* M2al, half_t* M2bh,
                         half_t* M2bl) {
    int i = blockIdx.x * blockDim.x + threadIdx.x;
    if (i < 114688) {
        wcv(l1, W1h, W1l, 7, 128, 128, i);  // concat-K layout for layer-1
    } else if (i < 172032) {
        // W2: concat-N layout. B^T[np][k], np = km*64+n, value = l2[km][k][n]
        int j = i - 114688;
        int np = j >> 7, k = j & 127;
        int km = np >> 6, n = np & 63;
        float w = l2[(size_t)km * 128 * 64 + (size_t)k * 64 + n];
        half_t h = (half_t)w;
        W2h[j] = h;
        W2l[j] = (half_t)((w - (float)h) * 1024.f);
    } else if (i < 204800) {
        wcv(a1, M1ah, M1al, 1, 128, 256, i - 172032);
    } else if (i < 237568) {
        wcv(b1, M1bh, M1bl, 1, 256, 128, i - 204800);
    } else if (i < 245760) {
        wcv(a2, M2ah, M2al, 1, 64, 128, i - 237568);
    } else if (i < 253952) {
        wcv(b2, M2bh, M2bl, 1, 128, 64, i - 245760);
    }
}

// stage A: partial[k-1][p][c] = sum_{kk=p*16..p*16+15} l2[k][kk][c]
// grid 48 = (k-1)*8 + p, 256 threads: c = tid&63, q = tid>>6 sums 4 kk each.
__global__ void trows_part(const float* __restrict__ l2, float* __restrict__ partial) {
    __shared__ float sm[256];
    int k = blockIdx.x / 8 + 1;
    int p = blockIdx.x % 8;
    int c = threadIdx.x & 63;
    int q = threadIdx.x >> 6;
    float a = 0.f;
    int kk0 = p * 16 + q * 4;
#pragma unroll
    for (int t = 0; t < 4; ++t)
        a += l2[(size_t)k * 128 * 64 + (kk0 + t) * 64 + c];
    sm[threadIdx.x] = a;
    __syncthreads();
    if (q == 0)
        partial[(size_t)blockIdx.x * 64 + c] =
            (sm[c] + sm[64 + c]) + (sm[128 + c] + sm[192 + c]);
}

// stage B: T[j][c] = sum_{k=j+1..6} sum_p partial[k-1][p][c]
__global__ void trows_final(const float* __restrict__ partial, float* __restrict__ T) {
    int j = threadIdx.x >> 6;
    int c = threadIdx.x & 63;
    if (j >= 6) return;
    float a = 0.f;
    for (int k = j + 1; k <= 6; ++k)
#pragma unroll
        for (int p = 0; p < 8; ++p) a += partial[(size_t)((k - 1) * 8 + p) * 64 + c];
    T[j * 64 + c] = a;
}

// ---------------- propagation, 128ch (layer 1), 8-deep ----------------

__global__ void __launch_bounds__(256) prop(const unsigned* __restrict__ gin, int idl,
                                            unsigned* __restrict__ gout, int odl,
                                            const float* __restrict__ dis,
                                            const int* __restrict__ off,
                                            const unsigned short* __restrict__ esrc, int N) {
    const int lane = threadIdx.x & 63;
    const int w = threadIdx.x >> 6;
    const int stride = gridDim.x * 4;
    for (int v = blockIdx.x * 4 + w; v < N; v += stride) {
        int s = off[v], e = off[v + 1];
        float2 A0 = {0.f, 0.f}, A1 = {0.f, 0.f}, A2 = {0.f, 0.f}, A3 = {0.f, 0.f};
        float2 A4 = {0.f, 0.f}, A5 = {0.f, 0.f}, A6 = {0.f, 0.f}, A7 = {0.f, 0.f};
        for (int i = s; i < e; i += 8) {
            unsigned p[8];
            int ok[8];
#pragma unroll
            for (int j = 0; j < 8; ++j) {
                int ij = i + j;
                ok[j] = ij < e;
                int idx = ok[j] ? ij : e - 1;
                p[j] = gin[esrc[idx] * idl + lane];
            }
            A0.x += ok[0] ? hlo(p[0]) : 0.f; A0.y += ok[0] ? hhi(p[0]) : 0.f;
            A1.x += ok[1] ? hlo(p[1]) : 0.f; A1.y += ok[1] ? hhi(p[1]) : 0.f;
            A2.x += ok[2] ? hlo(p[2]) : 0.f; A2.y += ok[2] ? hhi(p[2]) : 0.f;
            A3.x += ok[3] ? hlo(p[3]) : 0.f; A3.y += ok[3] ? hhi(p[3]) : 0.f;
            A4.x += ok[4] ? hlo(p[4]) : 0.f; A4.y += ok[4] ? hhi(p[4]) : 0.f;
            A5.x += ok[5] ? hlo(p[5]) : 0.f; A5.y += ok[5] ? hhi(p[5]) : 0.f;
            A6.x += ok[6] ? hlo(p[6]) : 0.f; A6.y += ok[6] ? hhi(p[6]) : 0.f;
            A7.x += ok[7] ? hlo(p[7]) : 0.f; A7.y += ok[7] ? hhi(p[7]) : 0.f;
        }
        float ax = ((A0.x + A1.x) + (A2.x + A3.x)) + ((A4.x + A5.x) + (A6.x + A7.x));
        float ay = ((A0.y + A1.y) + (A2.y + A3.y)) + ((A4.y + A5.y) + (A6.y + A7.y));
        float dv = dis[v];
        float ce = (float)(e - s) * EPS_MSG;
        float hx = fmaf(dv, ax, ce);
        float hy = fmaf(dv, ay, ce);
        gout[v * odl + lane] = fpack2(dv * hx, dv * hy);
    }
}

// ---------------- propagation, 64ch Horner step (layer 2), 8-deep ----------

template <int FINAL>
__global__ void __launch_bounds__(256) prop64(
    const half_t* __restrict__ uin, int ldu, const half_t* __restrict__ pj, int ldp,
    half_t* __restrict__ uout, int ldo, const float* __restrict__ dis,
    const int* __restrict__ off, const unsigned short* __restrict__ esrc,
    const float* __restrict__ tj, const float* __restrict__ bias2, int N) {
    const int c = threadIdx.x & 63;
    const int w = threadIdx.x >> 6;
    const int stride = gridDim.x * 4;
    for (int v = blockIdx.x * 4 + w; v < N; v += stride) {
        int s = off[v], e = off[v + 1];
        float a0 = 0.f, a1 = 0.f, a2 = 0.f, a3 = 0.f;
        float a4 = 0.f, a5 = 0.f, a6 = 0.f, a7 = 0.f;
        for (int i = s; i < e; i += 8) {
            float q[8];
            int ok[8];
#pragma unroll
            for (int j = 0; j < 8; ++j) {
                int ij = i + j;
                ok[j] = ij < e;
                int idx = ok[j] ? ij : e - 1;
                q[j] = (float)uin[(size_t)esrc[idx] * ldu + c];
            }
            a0 += ok[0] ? q[0] : 0.f;
            a1 += ok[1] ? q[1] : 0.f;
            a2 += ok[2] ? q[2] : 0.f;
            a3 += ok[3] ? q[3] : 0.f;
            a4 += ok[4] ? q[4] : 0.f;
            a5 += ok[5] ? q[5] : 0.f;
            a6 += ok[6] ? q[6] : 0.f;
            a7 += ok[7] ? q[7] : 0.f;
        }
        float acc = ((a0 + a1) + (a2 + a3)) + ((a4 + a5) + (a6 + a7));
        float dv = dis[v];
        float base = (float)pj[(size_t)v * ldp + c] + (float)(e - s) * EPS_MSG * tj[c];
        float u = fmaf(dv, acc, base);
        if (FINAL)
            uout[(size_t)v * ldo + c] = (half_t)(u + bias2[c]);
        else
            uout[(size_t)v * ldo + c] = (half_t)(dv * u);
    }
}

// ---------------- concat GEMM: BM=128, BN=128, BK=32, 512 thr, dbuf ---------

__global__ __launch_bounds__(512) void gemmc(
    int M, int kiters, const half_t* __restrict__ A, int lda,
    const half_t* __restrict__ Bhp, const half_t* __restrict__ Blp, int ldb,
    half_t* __restrict__ Cp, int ldc, const float* __restrict__ rs,
    const float* __restrict__ bias) {
    constexpr int ABY = 8192, BBY = 8192, BUFBY = ABY + 2 * BBY;  // 24576
    __shared__ __align__(16) char lds[2][BUFBY];

    const int tid = threadIdx.x, lane = tid & 63, w = tid >> 6;  // 8 waves
    const int wr = w >> 1, wc = w & 1;
    const int m0 = blockIdx.x * 128;
    const int l15 = lane & 15, lq = lane >> 4;
    const int lr = lane >> 2, lc = lane & 3;

    const char* gA = (const char*)A;
    const char* gBh = (const char*)Bhp;
    const char* gBl = (const char*)Blp;
    const size_t ldaB = (size_t)lda * 2, ldbB = (size_t)ldb * 2;

    auto stage = [&](int kt, int buf) {
        const int k0b = kt * 64;
        char* base = lds[0] + buf * BUFBY;
        int r = w * 16 + lr;
        int sc = (lc ^ (r & 3)) << 4;
        {
            int gv = m0 + r;
            if (gv >= M) gv = M - 1;
            gld16(gA + (size_t)gv * ldaB + k0b + sc, base + w * 1024);
        }
        {
            size_t goff = (size_t)r * ldbB + k0b + sc;
            gld16(gBh + goff, base + ABY + w * 1024);
            gld16(gBl + goff, base + ABY + BBY + w * 1024);
        }
    };

    f32x4 acch[2][4], accl[2][4];
#pragma unroll
    for (int fm = 0; fm < 2; ++fm)
#pragma unroll
        for (int fn = 0; fn < 4; ++fn) {
            acch[fm][fn] = (f32x4){0.f, 0.f, 0.f, 0.f};
            accl[fm][fn] = (f32x4){0.f, 0.f, 0.f, 0.f};
        }

    auto compute = [&](int buf) {
        const char* Ab = lds[0] + buf * BUFBY;
        const char* Bhb = Ab + ABY;
        const char* Blb = Ab + ABY + BBY;
        f16x8 af[2];
#pragma unroll
        for (int fm = 0; fm < 2; ++fm) {
            int ra = wr * 32 + fm * 16 + l15;
            af[fm] = *(const f16x8*)(Ab + ra * 64 + ((lq ^ (ra & 3)) << 4));
        }
#pragma unroll
        for (int fn = 0; fn < 4; ++fn) {
            int rb = wc * 64 + fn * 16 + l15;
            int o = rb * 64 + ((lq ^ (rb & 3)) << 4);
            f16x8 bhv = *(const f16x8*)(Bhb + o);
            f16x8 blv = *(const f16x8*)(Blb + o);
#pragma unroll
            for (int fm = 0; fm < 2; ++fm) {
                acch[fm][fn] = __builtin_amdgcn_mfma_f32_16x16x32_f16(af[fm], bhv, acch[fm][fn], 0, 0, 0);
                accl[fm][fn] = __builtin_amdgcn_mfma_f32_16x16x32_f16(af[fm], blv, accl[fm][fn], 0, 0, 0);
            }
        }
    };

    stage(0, 0);
    int buf = 0;
    for (int kt = 0; kt < kiters; ++kt) {
        __syncthreads();
        if (kt + 1 < kiters) stage(kt + 1, buf ^ 1);
        compute(buf);
        buf ^= 1;
    }

#pragma unroll
    for (int fm = 0; fm < 2; ++fm)
#pragma unroll
        for (int fn = 0; fn < 4; ++fn)
#pragma unroll
            for (int i = 0; i < 4; ++i) {
                int gr = m0 + wr * 32 + fm * 16 + lq * 4 + i;
                if (gr >= M) continue;
                int gc = wc * 64 + fn * 16 + l15;
                float v = acch[fm][fn][i] + accl[fm][fn][i] * LO_INV;
                v = v * rs[gr] + bias[gc];
                Cp[(size_t)gr * ldc + gc] = (half_t)v;
            }
}

// ---------------- loop-N GEMM: A staged once, B dbuf per strip-tile ----------

template <int KT, int NS, int OUTF32>
__global__ __launch_bounds__(256) void gemmn(
    int M, const half_t* __restrict__ A, int lda, const half_t* __restrict__ Bhp,
    const half_t* __restrict__ Blp, int ldb, void* __restrict__ Cp, int ldc, int epi,
    const float* __restrict__ bias, const float* __restrict__ bng,
    const float* __restrict__ bnb, const float* __restrict__ scaleRows, int scaleStrip) {
    constexpr int KI = KT / 32;
    constexpr int T = NS * KI;
    constexpr int CPR = KT / 8;
    constexpr int LPR = CPR;
    constexpr int RPC = 64 / LPR;
    constexpr int SW = (CPR < 16) ? CPR - 1 : 15;
    constexpr int ACH = (64 * KT * 2) / 1024;
    constexpr int ACW = ACH / 4;
    constexpr int ABY = 64 * KT * 2;
    constexpr int BPB = 4096;
    __shared__ __align__(16) char lds[ABY + 4 * BPB];

    const int tid = threadIdx.x, lane = tid & 63, w = tid >> 6;
    const int m0 = blockIdx.x * 64;
    const int l15 = lane & 15, lq = lane >> 4;
    const int lr = lane >> 2, lc = lane & 3;

    const char* gA = (const char*)A;
    const char* gBh = (const char*)Bhp;
    const char* gBl = (const char*)Blp;
    const size_t ldaB = (size_t)lda * 2, ldbB = (size_t)ldb * 2;

#pragma unroll
    for (int i = 0; i < ACW; ++i) {
        int c = w * ACW + i;
        int r = c * RPC + lane / LPR;
        int col = lane % LPR;
        int scol = col ^ (r & SW);
        int gv = m0 + r;
        if (gv >= M) gv = M - 1;
        gld16(gA + (size_t)gv * ldaB + scol * 16, lds + c * 1024);
    }

    auto stageB = [&](int ns, int kt, int buf) {
        char* bb = lds + ABY + buf * 2 * BPB;
        int r = w * 16 + lr;
        int sc = (lc ^ (r & 3)) << 4;
        size_t goff = (size_t)(ns * 64 + r) * ldbB + kt * 64 + sc;
        gld16(gBh + goff, bb + w * 1024);
        gld16(gBl + goff, bb + BPB + w * 1024);
    };

    f32x4 acch[4], accl[4];

    auto compute = [&](int buf, int kt) {
        const char* Ab = lds;
        const char* Bhb = lds + ABY + buf * 2 * BPB;
        const char* Blb = Bhb + BPB;
        int ra = w * 16 + l15;
        int cc = kt * 4 + lq;
        f16x8 af = *(const f16x8*)(Ab + ra * (KT * 2) + ((cc ^ (ra & SW)) << 4));
#pragma unroll
        for (int fn = 0; fn < 4; ++fn) {
            int rb = fn * 16 + l15;
            int o = rb * 64 + ((lq ^ (rb & 3)) << 4);
            f16x8 bhv = *(const f16x8*)(Bhb + o);
            f16x8 blv = *(const f16x8*)(Blb + o);
            acch[fn] = __builtin_amdgcn_mfma_f32_16x16x32_f16(af, bhv, acch[fn], 0, 0, 0);
            accl[fn] = __builtin_amdgcn_mfma_f32_16x16x32_f16(af, blv, accl[fn], 0, 0, 0);
        }
    };

    stageB(0, 0, 0);
    int buf = 0;
    for (int t = 0; t < T; ++t) {
        int ns = t / KI, kt = t - ns * KI;
        __syncthreads();
        if (t + 1 < T) {
            int t1 = t + 1;
            stageB(t1 / KI, t1 - (t1 / KI) * KI, buf ^ 1);
        }
        if (kt == 0) {
#pragma unroll
            for (int fn = 0; fn < 4; ++fn) {
                acch[fn] = (f32x4){0.f, 0.f, 0.f, 0.f};
                accl[fn] = (f32x4){0.f, 0.f, 0.f, 0.f};
            }
        }
        compute(buf, kt);
        if (kt == KI - 1) {
#pragma unroll
            for (int fn = 0; fn < 4; ++fn)
#pragma unroll
                for (int i = 0; i < 4; ++i) {
                    int gr = m0 + w * 16 + lq * 4 + i;
                    if (gr >= M) continue;
                    int gc = ns * 64 + fn * 16 + l15;
                    float v = acch[fn][i] + accl[fn][i] * LO_INV;
                    if (ns == scaleStrip) v *= scaleRows[gr];
                    v = epi_apply(v, gc, epi, bias, bng, bnb);
                    if (OUTF32)
                        ((float*)Cp)[(size_t)gr * ldc + gc] = v;
                    else
                        ((half_t*)Cp)[(size_t)gr * ldc + gc] = (half_t)v;
                }
        }
        buf ^= 1;
    }
}

extern "C" void kernel_launch(void* const* d_in, const int* in_sizes, int n_in,
                              void* d_out, int out_size, void* d_ws, size_t ws_size,
                              hipStream_t stream) {
    const float* x     = (const float*)d_in[0];
    const int*   ei    = (const int*)d_in[1];
    const float* lins1 = (const float*)d_in[2];
    const float* bias1 = (const float*)d_in[3];
    const float* m1w1  = (const float*)d_in[4];
    const float* m1b1  = (const float*)d_in[5];
    const float* bn1g  = (const float*)d_in[6];
    const float* bn1b  = (const float*)d_in[7];
    const float* m1w2  = (const float*)d_in[8];
    const float* m1b2  = (const float*)d_in[9];
    const float* lins2 = (const float*)d_in[10];
    const float* bias2 = (const float*)d_in[11];
    const float* m2w1  = (const float*)d_in[12];
    const float* m2b1  = (const float*)d_in[13];
    const float* bn2g  = (const float*)d_in[14];
    const float* bn2b  = (const float*)d_in[15];
    const float* m2w2  = (const float*)d_in[16];
    const float* m2b2  = (const float*)d_in[17];
    float* out = (float*)d_out;

    const int N = in_sizes[0] / 128;
    const int E = in_sizes[1] / 2;
    const int* row = ei;
    const int* col = ei + E;

    char* ws = (char*)d_ws;
    size_t o = 0;
    auto alloc = [&](size_t bytes) {
        void* p = ws + o;
        o += (bytes + 255) & ~(size_t)255;
        return p;
    };
    int*            deg  = (int*)alloc((size_t)N * 4);
    int*            cur  = (int*)alloc((size_t)N * 4);
    float*          dis  = (float*)alloc((size_t)N * 4);
    float*          sA   = (float*)alloc((size_t)N * 4);
    float*          rsA  = (float*)alloc((size_t)N * 4);
    int*            off  = (int*)alloc((size_t)(N + 1) * 4);
    int*            bsum = (int*)alloc(1024 * 4);
    float*          Trow = (float*)alloc(6 * 64 * 4);
    float*          Tpar = (float*)alloc(48 * 64 * 4);
    unsigned short* esrc = (unsigned short*)alloc((size_t)E * 2);
    half_t* g0    = (half_t*)alloc((size_t)N * 128 * 2);
    half_t* ACC   = (half_t*)alloc((size_t)N * 128 * 2);
    half_t* Z     = (half_t*)alloc((size_t)N * 256 * 2);
    half_t* H1    = (half_t*)alloc((size_t)N * 128 * 2);
    half_t* ACC2  = (half_t*)alloc((size_t)N * 64 * 2);
    half_t* Wc1h  = (half_t*)alloc((size_t)128 * 896 * 2);
    half_t* Wc1l  = (half_t*)alloc((size_t)128 * 896 * 2);
    half_t* Wc2h  = (half_t*)alloc((size_t)448 * 128 * 2);
    half_t* Wc2l  = (half_t*)alloc((size_t)448 * 128 * 2);
    half_t* Wm1ah = (half_t*)alloc((size_t)256 * 128 * 2);
    half_t* Wm1al = (half_t*)alloc((size_t)256 * 128 * 2);
    half_t* Wm1bh = (half_t*)alloc((size_t)128 * 256 * 2);
    half_t* Wm1bl = (half_t*)alloc((size_t)128 * 256 * 2);
    half_t* Wm2ah = (half_t*)alloc((size_t)128 * 64 * 2);
    half_t* Wm2al = (half_t*)alloc((size_t)128 * 64 * 2);
    half_t* Wm2bh = (half_t*)alloc((size_t)64 * 128 * 2);
    half_t* Wm2bl = (half_t*)alloc((size_t)64 * 128 * 2);
    half_t* slab  = (half_t*)alloc((size_t)N * 896 * 2);
    (void)ws_size;

    const int TPB = 256;
    const int nb = (N + 1023) / 1024;
    zero_i32<<<(N + TPB - 1) / TPB, TPB, 0, stream>>>(deg, N);
    zero_i32<<<(N + TPB - 1) / TPB, TPB, 0, stream>>>(cur, N);
    count_deg<<<(E + TPB - 1) / TPB, TPB, 0, stream>>>(col, deg, E);
    compute_dis_s<<<(N + TPB - 1) / TPB, TPB, 0, stream>>>(deg, dis, sA, rsA, N);
    scan_blk<<<nb, 1024, 0, stream>>>(deg, off, bsum, N);
    scan_top<<<1, 64, 0, stream>>>(bsum, nb);
    scan_add<<<nb, 1024, 0, stream>>>(off, bsum, N);
    fill_edges<<<(E + TPB - 1) / TPB, TPB, 0, stream>>>(row, col, off, cur, esrc, E);
    conv_all<<<(253952 + TPB - 1) / TPB, TPB, 0, stream>>>(
        lins1, lins2, m1w1, m1w2, m2w1, m2w2, Wc1h, Wc1l, Wc2h, Wc2l, Wm1ah, Wm1al, Wm1bh,
        Wm1bl, Wm2ah, Wm2al, Wm2bh, Wm2bl);
    trows_part<<<48, 256, 0, stream>>>(lins2, Tpar);
    trows_final<<<1, 384, 0, stream>>>(Tpar, Trow);
    conv_xg<<<(N * 128 + TPB - 1) / TPB, TPB, 0, stream>>>(x, slab, g0, dis, sA, N * 128);

    unsigned* slabU = (unsigned*)slab;
    unsigned* g0U = (unsigned*)g0;
    const int HG = (N + 63) / 64;
    const int HG128 = (N + 127) / 128;

    // ---- Layer 1: 6 props @128ch into slab cols 1..6, concat-K GEMM ----
    prop<<<2048, 256, 0, stream>>>(g0U, 64, slabU + 64, 448, dis, off, esrc, N);
    for (int k = 2; k <= 6; ++k)
        prop<<<2048, 256, 0, stream>>>(slabU + (size_t)(k - 1) * 64, 448,
                                       slabU + (size_t)k * 64, 448, dis, off, esrc, N);
    gemmc<<<HG128, 512, 0, stream>>>(N, 28, slab, 896, Wc1h, Wc1l, 896, ACC, 128, rsA, bias1);
    // MLP1: Z = relu(bn(ACC@W+b)); h1 = relu(Z@W+b) -> H1
    gemmn<128, 4, 0><<<HG, 256, 0, stream>>>(
        N, ACC, 128, Wm1ah, Wm1al, 128, Z, 256, 2, m1b1, bn1g, bn1b, nullptr, -1);
    gemmn<256, 2, 0><<<HG, 256, 0, stream>>>(
        N, Z, 256, Wm1bh, Wm1bl, 256, H1, 128, 3, m1b2, nullptr, nullptr, nullptr, -1);

    // ---- Layer 2: P = H1 @ [W2_0..W2_6] (concat-N); strip 6 pre-scaled by dis ----
    gemmn<128, 7, 0><<<HG, 256, 0, stream>>>(
        N, H1, 128, Wc2h, Wc2l, 128, slab, 448, 0, nullptr, nullptr, nullptr, dis, 6);

    // ---- Horner: u <- p_j + EPS*indeg*t_j + M u, 6 steps @64ch ----
    half_t* ub0 = g0;
    half_t* ub1 = g0 + (size_t)N * 64;
    prop64<0><<<2048, 256, 0, stream>>>(slab + 384, 448, slab + 320, 448, ub0, 64, dis, off,
                                        esrc, Trow + 5 * 64, nullptr, N);
    prop64<0><<<2048, 256, 0, stream>>>(ub0, 64, slab + 256, 448, ub1, 64, dis, off, esrc,
                                        Trow + 4 * 64, nullptr, N);
    prop64<0><<<2048, 256, 0, stream>>>(ub1, 64, slab + 192, 448, ub0, 64, dis, off, esrc,
                                        Trow + 3 * 64, nullptr, N);
    prop64<0><<<2048, 256, 0, stream>>>(ub0, 64, slab + 128, 448, ub1, 64, dis, off, esrc,
                                        Trow + 2 * 64, nullptr, N);
    prop64<0><<<2048, 256, 0, stream>>>(ub1, 64, slab + 64, 448, ub0, 64, dis, off, esrc,
                                        Trow + 1 * 64, nullptr, N);
    prop64<1><<<2048, 256, 0, stream>>>(ub0, 64, slab, 448, ACC2, 64, dis, off, esrc,
                                        Trow + 0 * 64, bias2, N);

    // ---- MLP2 ----
    gemmn<64, 2, 0><<<HG, 256, 0, stream>>>(
        N, ACC2, 64, Wm2ah, Wm2al, 64, Z, 128, 2, m2b1, bn2g, bn2b, nullptr, -1);
    gemmn<128, 1, 1><<<HG, 256, 0, stream>>>(
        N, Z, 128, Wm2bh, Wm2bl, 128, out, 64, 1, m2b2, nullptr, nullptr, nullptr, -1);
}